// Round 6
// baseline (327.121 us; speedup 1.0000x reference)
//
#include <hip/hip_runtime.h>
#include <hip/hip_bf16.h>
#include <cstdint>
#include <cstddef>

typedef _Float16 f16;
typedef _Float16 f16x8 __attribute__((ext_vector_type(8)));
typedef _Float16 f16x4 __attribute__((ext_vector_type(4)));
typedef float    f32x4 __attribute__((ext_vector_type(4)));

constexpr int Bdim = 16, Ndim = 4096, Sdim = 1024;
constexpr int C1 = 256, C2 = 512, CIN = 768, H = 256;

// ---------------------------------------------------------------- async copy
__device__ __forceinline__ void async16(void* l, const void* g) {
  __builtin_amdgcn_global_load_lds(
      reinterpret_cast<__attribute__((address_space(1))) char*>(
          reinterpret_cast<uintptr_t>(g)),
      reinterpret_cast<__attribute__((address_space(3))) char*>(
          reinterpret_cast<uintptr_t>(l)),
      16, 0, 0);
}

// ---------------------------------------------------------------- prep
// Adds the knn B-panel build: per known point s, a 24-f16 (48B) row:
// chunk0 = [khx,klx,khx,klx, khy,kly,khy,kly], chunk1 = [khz,klz,khz,klz, skh,skl,0,0]
// where kh/kl = fp16 hi/lo split of (-2*coord), sk split likewise; chunk2 = pad.
__global__ void prep_kernel(const float* __restrict__ W1, const float* __restrict__ W2,
    const float* __restrict__ b1, const float* __restrict__ g1, const float* __restrict__ be1,
    const float* __restrict__ mu1, const float* __restrict__ va1,
    const float* __restrict__ b2, const float* __restrict__ g2, const float* __restrict__ be2,
    const float* __restrict__ mu2, const float* __restrict__ va2,
    const float* __restrict__ known,
    f16* __restrict__ W1h, f16* __restrict__ W2h, f16* __restrict__ bpanel,
    float* __restrict__ s1, float* __restrict__ t1,
    float* __restrict__ s2, float* __restrict__ t2)
{
  int i = blockIdx.x * 256 + threadIdx.x;
  if (i < H * CIN) W1h[i] = (f16)W1[i];
  if (i < H * H)   W2h[i] = (f16)W2[i];
  if (i < Bdim * Sdim) {
    const float* kp = known + (size_t)i * 3;
    float kx = kp[0], ky = kp[1], kz = kp[2];
    float sk = kx * kx + ky * ky + kz * kz;
    float mx = -2.0f * kx, my = -2.0f * ky, mz = -2.0f * kz;
    f16 hx = (f16)mx, lx = (f16)(mx - (float)hx);
    f16 hy = (f16)my, ly = (f16)(my - (float)hy);
    f16 hz = (f16)mz, lz = (f16)(mz - (float)hz);
    f16 hs = (f16)sk, ls = (f16)(sk - (float)hs);
    f16* d = bpanel + (size_t)i * 24;
    d[0] = hx; d[1] = lx; d[2]  = hx; d[3]  = lx;
    d[4] = hy; d[5] = ly; d[6]  = hy; d[7]  = ly;
    d[8] = hz; d[9] = lz; d[10] = hz; d[11] = lz;
    d[12] = hs; d[13] = ls; d[14] = (f16)0.f; d[15] = (f16)0.f;
#pragma unroll
    for (int q = 16; q < 24; ++q) d[q] = (f16)0.f;
  }
  if (i < H) {
    float sc1 = g1[i] / sqrtf(va1[i] + 1e-5f);
    s1[i] = sc1; t1[i] = b1[i] * sc1 + be1[i] - mu1[i] * sc1;
    float sc2 = g2[i] / sqrtf(va2[i] + 1e-5f);
    s2[i] = sc2; t2[i] = b2[i] * sc2 + be2[i] - mu2[i] * sc2;
  }
}

// ---------------------------------------------------------------- 3-NN (v4, MFMA)
__device__ __forceinline__ void top3_insert(float pd, int pi,
    float& d0, float& d1, float& d2v, int& i0, int& i1, int& i2)
{
  bool c0 = (pd < d0) || (pd == d0 && pi < i0);
  bool c1 = (pd < d1) || (pd == d1 && pi < i1);
  bool c2 = (pd < d2v) || (pd == d2v && pi < i2);
  d2v = c1 ? d1 : (c2 ? pd : d2v);
  i2  = c1 ? i1 : (c2 ? pi : i2);
  d1  = c0 ? d0 : (c1 ? pd : d1);
  i1  = c0 ? i0 : (c1 ? pi : i1);
  d0  = c0 ? pd : d0;
  i0  = c0 ? pi : i0;
}

__global__ __launch_bounds__(512)
void knn_kernel(const float* __restrict__ unknown, const f16* __restrict__ bpanel,
                int* __restrict__ idx3, float* __restrict__ w3)
{
  __shared__ f16  Blds[Sdim * 24];     // 49152 B, 48B/point rows (chunk2 pad)
  __shared__ f16  Alds[8 * 16 * 24];   // 6144 B
  __shared__ float su_lds[8 * 16];
  __shared__ int   cnt[128];
  __shared__ float cd[128][8];
  __shared__ int   ci[128][8];

  int t = threadIdx.x;
  int b = blockIdx.y;
  int lane = t & 63, w = t >> 6;
  int r = lane & 15, g = lane >> 4;

  if (t < 128) cnt[t] = 0;

  // stage B-panel (48 KB, linear copy; global layout == LDS layout)
  {
    const f16* bp = bpanel + (size_t)b * Sdim * 24;
#pragma unroll
    for (int i = 0; i < 6; ++i) {
      int c = t + i * 512;
      async16((char*)Blds + c * 16, (const char*)bp + c * 16);
    }
  }

  // build A rows (16 queries per wave)
  int n0 = blockIdx.x * 128 + w * 16;
  if (lane < 16) {
    int n = n0 + lane;
    const float* up = unknown + ((size_t)b * Ndim + n) * 3;
    float x = up[0], y = up[1], z = up[2];
    su_lds[w * 16 + lane] = x * x + y * y + z * z;
    f16 hx = (f16)x, lx = (f16)(x - (float)hx);
    f16 hy = (f16)y, ly = (f16)(y - (float)hy);
    f16 hz = (f16)z, lz = (f16)(z - (float)hz);
    f16* ar = Alds + (w * 16 + lane) * 24;
    f16x8 c0 = {hx, hx, lx, lx, hy, hy, ly, ly};
    f16x8 c1 = {hz, hz, lz, lz, (f16)1.f, (f16)1.f, (f16)0.f, (f16)0.f};
    *(f16x8*)ar = c0;
    *(f16x8*)(ar + 8) = c1;
  }
  __syncthreads();

  // lane-constant fragment state
  f16x8 af = {};
  if (g < 2) af = *(const f16x8*)(Alds + (w * 16 + r) * 24 + g * 8);
  f32x4 su4;
#pragma unroll
  for (int j = 0; j < 4; ++j) su4[j] = su_lds[w * 16 + g * 4 + j];
  int boff = r * 24 + (g & 1) * 8;     // g>=2 mirrors g&1 -> broadcast pair

  // ---- pass 1: top-3 distance values
  float t0_[4], t1_[4], t2_[4];
#pragma unroll
  for (int j = 0; j < 4; ++j) { t0_[j] = 1e30f; t1_[j] = 1e30f; t2_[j] = 1e30f; }

#pragma unroll 4
  for (int T = 0; T < 64; ++T) {
    f16x8 bf = *(const f16x8*)(Blds + T * 384 + boff);
    f32x4 acc = su4;
    acc = __builtin_amdgcn_mfma_f32_16x16x32_f16(af, bf, acc, 0, 0, 0);
#pragma unroll
    for (int j = 0; j < 4; ++j) {
      float d = acc[j];
      t2_[j] = __builtin_amdgcn_fmed3f(t1_[j], t2_[j], d);
      t1_[j] = __builtin_amdgcn_fmed3f(t0_[j], t1_[j], d);
      t0_[j] = fminf(t0_[j], d);
    }
  }

  // ---- merge sorted triples across the 16 cols (shfl within 16-lane group)
#pragma unroll
  for (int m = 1; m < 16; m <<= 1) {
#pragma unroll
    for (int j = 0; j < 4; ++j) {
      float b0 = __shfl_xor(t0_[j], m), b1 = __shfl_xor(t1_[j], m), b2 = __shfl_xor(t2_[j], m);
      float n0m = fminf(t0_[j], b0);
      float n1m = fminf(fmaxf(t0_[j], b0), fminf(t1_[j], b1));
      float n2m = fminf(fminf(fmaxf(t0_[j], b1), fmaxf(t1_[j], b0)), fminf(t2_[j], b2));
      t0_[j] = n0m; t1_[j] = n1m; t2_[j] = n2m;
    }
  }
  // t2_[j] = exact 3rd-smallest distance for query g*4+j (all 16 lanes agree)

  // ---- pass 2: bitwise-identical rescan, collect candidates
#pragma unroll 2
  for (int T = 0; T < 64; ++T) {
    f16x8 bf = *(const f16x8*)(Blds + T * 384 + boff);
    f32x4 acc = su4;
    acc = __builtin_amdgcn_mfma_f32_16x16x32_f16(af, bf, acc, 0, 0, 0);
    bool h = (acc[0] <= t2_[0]) | (acc[1] <= t2_[1]) |
             (acc[2] <= t2_[2]) | (acc[3] <= t2_[3]);
    if (h) {
#pragma unroll
      for (int j = 0; j < 4; ++j) {
        if (acc[j] <= t2_[j]) {
          int q = w * 16 + g * 4 + j;
          int slot = atomicAdd(&cnt[q], 1);
          if (slot < 8) { cd[q][slot] = acc[j]; ci[q][slot] = T * 16 + r; }
        }
      }
    }
  }
  __syncthreads();

  // ---- finalize: exact (d, idx) sort of candidates, weights, store
  if (t < 128) {
    int q = t;
    float d0 = 1e30f, d1 = 1e30f, d2v = 1e30f;
    int i0 = 0x7fffffff, i1 = 0x7fffffff, i2 = 0x7fffffff;
    int mc = cnt[q] < 8 ? cnt[q] : 8;
#pragma unroll
    for (int i = 0; i < 8; ++i)
      if (i < mc) top3_insert(cd[q][i], ci[q][i], d0, d1, d2v, i0, i1, i2);
    float wa = 1.0f / (d0 + 1e-8f);
    float wb = 1.0f / (d1 + 1e-8f);
    float wc = 1.0f / (d2v + 1e-8f);
    float wsum = wa + wb + wc;
    int n = blockIdx.x * 128 + q;
    int p = b * Ndim + n;
    idx3[3 * p] = i0; idx3[3 * p + 1] = i1; idx3[3 * p + 2] = i2;
    w3[3 * p] = wa / wsum; w3[3 * p + 1] = wb / wsum; w3[3 * p + 2] = wc / wsum;
  }
}

// ---------------------------------------------------------------- transpose+cast
// in: fp32 (R, C) row-major per batch; out: fp16, out[c*ldo + r] per batch
__global__ void transpose_cast(const float* __restrict__ in, f16* __restrict__ out,
                               int R, int C, int ldo, long inBStride, long outBStride)
{
  __shared__ float tile[32][33];
  const float* src = in + blockIdx.z * inBStride;
  f16* dst = out + blockIdx.z * outBStride;
  int r0 = blockIdx.y * 32, c0 = blockIdx.x * 32;
  int tx = threadIdx.x & 31, ty = threadIdx.x >> 5;  // ty 0..7
#pragma unroll
  for (int i = 0; i < 4; ++i)
    tile[ty + i * 8][tx] = src[(size_t)(r0 + ty + i * 8) * C + c0 + tx];
  __syncthreads();
#pragma unroll
  for (int i = 0; i < 4; ++i)
    dst[(size_t)(c0 + ty + i * 8) * ldo + r0 + tx] = (f16)tile[tx][ty + i * 8];
}

// ---------------------------------------------------------------- interpolation (v3)
__global__ __launch_bounds__(256)
void interp_kernel(const f16* __restrict__ kfT, const int* __restrict__ idx3,
                   const float* __restrict__ w3, f16* __restrict__ feat)
{
  int t = threadIdx.x;
  int wv = t >> 6, l = t & 63;
  int ptbase = blockIdx.x * 32 + wv * 8;
#pragma unroll
  for (int i = 0; i < 8; ++i) {
    int pt = ptbase + i;
    int b = pt >> 12;
    int i0 = idx3[3 * pt], i1 = idx3[3 * pt + 1], i2 = idx3[3 * pt + 2];
    float w0 = w3[3 * pt], w1 = w3[3 * pt + 1], w2 = w3[3 * pt + 2];
    const f16* base = kfT + ((size_t)b << 10) * C2;
    f16x8 a = *((const f16x8*)(base + (size_t)i0 * C2) + l);
    f16x8 c = *((const f16x8*)(base + (size_t)i1 * C2) + l);
    f16x8 d = *((const f16x8*)(base + (size_t)i2 * C2) + l);
    f16x8 o;
#pragma unroll
    for (int j = 0; j < 8; ++j)
      o[j] = (f16)(w0 * (float)a[j] + w1 * (float)c[j] + w2 * (float)d[j]);
    *((f16x8*)(feat + (size_t)pt * CIN + C1) + l) = o;
  }
}

// ---------------------------------------------------------------- GEMM (v2: 128x128 tile, BK=32, 32KB LDS)
// D[m, col] = sum_k A[m,k] * Bt[col,k];  A: (Mtot,K) row-major, Bt: (Ntot,K) row-major.
// BK=32 double-buffer -> 32KB LDS/block -> 4 blocks/CU (VGPR-limited), vs 2 at BK=64.
// LDS row = 64B (4x16B chunks), involution swizzle chunk x <-> x^(row&3); worst 2-way
// bank aliasing on ds_read_b128 (free per m136). global_load_lds dest stays linear t*16.
// MODE 1: out = x1 fp16, x1[col*H + m] = relu(acc*scale[m]+shift[m])   (GEMM1: m=o, col=pt)
// MODE 2: out = fp32 d_out[(b*H+o)*N + n], pt=m, o=col                  (GEMM2)
template <int K, int MODE>
__global__ __launch_bounds__(256, 4)
void gemm_kernel(const f16* __restrict__ A, const f16* __restrict__ Bt,
                 const float* __restrict__ scale, const float* __restrict__ shift,
                 void* __restrict__ outp)
{
  __shared__ char lds[32768];  // 2 bufs x (A 8KB + B 8KB)

  int id = blockIdx.x;
  id = (id & 7) * 128 + (id >> 3);        // XCD-chunked swizzle, 1024 blocks
  int big = id >> 1, small = id & 1;
  int m0, n0;
  if (MODE == 1) { m0 = small * 128; n0 = big * 128; }
  else           { m0 = big * 128;  n0 = small * 128; }

  int t = threadIdx.x;
  int lane = t & 63, wid = t >> 6;
  int wm = wid >> 1, wn = wid & 1;
  int lr = lane & 15, lh = lane >> 4;

  f32x4 acc[4][4] = {};

  constexpr int NT = K / 32;
  const f16* Arow = A + (size_t)m0 * K;
  const f16* Brow = Bt + (size_t)n0 * K;
  int p = t >> 2, x = t & 3;              // row-within-64, chunk 0..3

  auto STAGE = [&](int buf, int kt) {
    int k0 = kt * 32;
    char* base = lds + buf * 16384;
#pragma unroll
    for (int r = 0; r < 2; ++r) {
      int row = r * 64 + p;
      int sw = (x ^ (row & 3)) * 8;       // involution swizzle on SOURCE (16B chunks)
      async16(base + r * 4096 + t * 16,        Arow + (size_t)row * K + k0 + sw);
      async16(base + 8192 + r * 4096 + t * 16, Brow + (size_t)row * K + k0 + sw);
    }
  };

  STAGE(0, 0);
  __syncthreads();
  int cur = 0;
  for (int kt = 0; kt < NT; ++kt) {
    if (kt + 1 < NT) STAGE(cur ^ 1, kt + 1);
    const char* Ab = lds + cur * 16384;
    const char* Bb = Ab + 8192;
    f16x8 af[4], bf[4];
#pragma unroll
    for (int mf = 0; mf < 4; ++mf) {
      int row = wm * 64 + mf * 16 + lr;
      af[mf] = *(const f16x8*)(Ab + row * 64 + ((lh ^ (row & 3)) << 4));
    }
#pragma unroll
    for (int nf = 0; nf < 4; ++nf) {
      int row = wn * 64 + nf * 16 + lr;
      bf[nf] = *(const f16x8*)(Bb + row * 64 + ((lh ^ (row & 3)) << 4));
    }
#pragma unroll
    for (int mf = 0; mf < 4; ++mf)
#pragma unroll
      for (int nf = 0; nf < 4; ++nf)
        acc[mf][nf] = __builtin_amdgcn_mfma_f32_16x16x32_f16(af[mf], bf[nf], acc[mf][nf], 0, 0, 0);
    __syncthreads();
    cur ^= 1;
  }

  if (MODE == 1) {
    f16* x1 = (f16*)outp;
#pragma unroll
    for (int mf = 0; mf < 4; ++mf) {
      int ob = m0 + wm * 64 + mf * 16 + lh * 4;   // 4 consecutive output channels
      f32x4 sc = *(const f32x4*)(scale + ob);
      f32x4 sh = *(const f32x4*)(shift + ob);
#pragma unroll
      for (int nf = 0; nf < 4; ++nf) {
        int ptc = n0 + wn * 64 + nf * 16 + lr;
        f16x4 v;
#pragma unroll
        for (int j = 0; j < 4; ++j) {
          float y = acc[mf][nf][j] * sc[j] + sh[j];
          v[j] = (f16)(y > 0.0f ? y : 0.0f);
        }
        *(f16x4*)(x1 + (size_t)ptc * H + ob) = v;
      }
    }
  } else {
    float* out = (float*)outp;
#pragma unroll
    for (int mf = 0; mf < 4; ++mf) {
      int ptb = m0 + wm * 64 + mf * 16 + lh * 4;  // 4 consecutive points
      int bb = ptb >> 12, nn = ptb & 4095;
#pragma unroll
      for (int nf = 0; nf < 4; ++nf) {
        int o = n0 + wn * 64 + nf * 16 + lr;
        float sc = scale[o], sh = shift[o];
        f32x4 v;
#pragma unroll
        for (int j = 0; j < 4; ++j) {
          float y = acc[mf][nf][j] * sc + sh;
          v[j] = (y > 0.0f ? y : 0.0f);
        }
        *(f32x4*)(out + ((size_t)(bb * H + o) << 12) + nn) = v;
      }
    }
  }
}

// ---------------------------------------------------------------- launch
extern "C" void kernel_launch(void* const* d_in, const int* in_sizes, int n_in,
                              void* d_out, int out_size, void* d_ws, size_t ws_size,
                              hipStream_t stream)
{
  (void)in_sizes; (void)n_in; (void)out_size; (void)ws_size;
  const float* unknown = (const float*)d_in[0];
  const float* known   = (const float*)d_in[1];
  const float* uf      = (const float*)d_in[2];
  const float* kf      = (const float*)d_in[3];
  const float* W1  = (const float*)d_in[4];
  const float* b1  = (const float*)d_in[5];
  const float* g1  = (const float*)d_in[6];
  const float* be1 = (const float*)d_in[7];
  const float* mu1 = (const float*)d_in[8];
  const float* va1 = (const float*)d_in[9];
  const float* W2  = (const float*)d_in[10];
  const float* b2  = (const float*)d_in[11];
  const float* g2  = (const float*)d_in[12];
  const float* be2 = (const float*)d_in[13];
  const float* mu2 = (const float*)d_in[14];
  const float* va2 = (const float*)d_in[15];

  char* ws = (char*)d_ws;
  f16*   W1h    = (f16*)(ws + 0);             //    393,216 B
  f16*   W2h    = (f16*)(ws + 393216);        //    131,072 B
  float* s1     = (float*)(ws + 524288);
  float* t1     = (float*)(ws + 525312);
  float* s2     = (float*)(ws + 526336);
  float* t2     = (float*)(ws + 527360);
  int*   idx3   = (int*)(ws + 528384);        //    786,432 B
  float* w3     = (float*)(ws + 1314816);     //    786,432 B
  f16*   bpanel = (f16*)(ws + 2101248);       //    786,432 B (16x1024x24 f16)
  f16*   kfT    = (f16*)(ws + 2887680);       // 16,777,216 B  (B,S,C2) fp16
  f16*   feat   = (f16*)(ws + 19664896);      // 100,663,296 B (pts, CIN) fp16
  f16*   x1     = (f16*)(ws + 120328192);     // 33,554,432 B  (pts, H) fp16
                                              // total 153,882,624 B

  prep_kernel<<<768, 256, 0, stream>>>(W1, W2, b1, g1, be1, mu1, va1,
                                       b2, g2, be2, mu2, va2, known,
                                       W1h, W2h, bpanel, s1, t1, s2, t2);
  knn_kernel<<<dim3(Ndim / 128, Bdim), 512, 0, stream>>>(unknown, bpanel, idx3, w3);
  transpose_cast<<<dim3(Sdim / 32, C2 / 32, Bdim), 256, 0, stream>>>(
      kf, kfT, C2, Sdim, C2, (long)C2 * Sdim, (long)Sdim * C2);
  transpose_cast<<<dim3(Ndim / 32, C1 / 32, Bdim), 256, 0, stream>>>(
      uf, feat, C1, Ndim, CIN, (long)C1 * Ndim, (long)Ndim * CIN);
  interp_kernel<<<(Bdim * Ndim) / 32, 256, 0, stream>>>(kfT, idx3, w3, feat);
  gemm_kernel<CIN, 1><<<1024, 256, 0, stream>>>(W1h, feat, s1, t1, x1);
  gemm_kernel<H,   2><<<1024, 256, 0, stream>>>(x1, W2h, s2, t2, d_out);
}

// Round 7
// 301.038 us; speedup vs baseline: 1.0866x; 1.0866x over previous
//
#include <hip/hip_runtime.h>
#include <hip/hip_bf16.h>
#include <cstdint>
#include <cstddef>

typedef _Float16 f16;
typedef _Float16 f16x8 __attribute__((ext_vector_type(8)));
typedef _Float16 f16x4 __attribute__((ext_vector_type(4)));
typedef float    f32x4 __attribute__((ext_vector_type(4)));

constexpr int Bdim = 16, Ndim = 4096, Sdim = 1024;
constexpr int C1 = 256, C2 = 512, CIN = 768, H = 256;

// ---------------------------------------------------------------- async copy
__device__ __forceinline__ void async16(void* l, const void* g) {
  __builtin_amdgcn_global_load_lds(
      reinterpret_cast<__attribute__((address_space(1))) char*>(
          reinterpret_cast<uintptr_t>(g)),
      reinterpret_cast<__attribute__((address_space(3))) char*>(
          reinterpret_cast<uintptr_t>(l)),
      16, 0, 0);
}

// ---------------------------------------------------------------- prep
__global__ void prep_kernel(const float* __restrict__ W1, const float* __restrict__ W2,
    const float* __restrict__ b1, const float* __restrict__ g1, const float* __restrict__ be1,
    const float* __restrict__ mu1, const float* __restrict__ va1,
    const float* __restrict__ b2, const float* __restrict__ g2, const float* __restrict__ be2,
    const float* __restrict__ mu2, const float* __restrict__ va2,
    const float* __restrict__ known,
    f16* __restrict__ W1h, f16* __restrict__ W2h, f16* __restrict__ bpanel,
    float* __restrict__ s1, float* __restrict__ t1,
    float* __restrict__ s2, float* __restrict__ t2)
{
  int i = blockIdx.x * 256 + threadIdx.x;
  if (i < H * CIN) W1h[i] = (f16)W1[i];
  if (i < H * H)   W2h[i] = (f16)W2[i];
  if (i < Bdim * Sdim) {
    const float* kp = known + (size_t)i * 3;
    float kx = kp[0], ky = kp[1], kz = kp[2];
    float sk = kx * kx + ky * ky + kz * kz;
    float mx = -2.0f * kx, my = -2.0f * ky, mz = -2.0f * kz;
    f16 hx = (f16)mx, lx = (f16)(mx - (float)hx);
    f16 hy = (f16)my, ly = (f16)(my - (float)hy);
    f16 hz = (f16)mz, lz = (f16)(mz - (float)hz);
    f16 hs = (f16)sk, ls = (f16)(sk - (float)hs);
    f16* d = bpanel + (size_t)i * 24;
    d[0] = hx; d[1] = lx; d[2]  = hx; d[3]  = lx;
    d[4] = hy; d[5] = ly; d[6]  = hy; d[7]  = ly;
    d[8] = hz; d[9] = lz; d[10] = hz; d[11] = lz;
    d[12] = hs; d[13] = ls; d[14] = (f16)0.f; d[15] = (f16)0.f;
#pragma unroll
    for (int q = 16; q < 24; ++q) d[q] = (f16)0.f;
  }
  if (i < H) {
    float sc1 = g1[i] / sqrtf(va1[i] + 1e-5f);
    s1[i] = sc1; t1[i] = b1[i] * sc1 + be1[i] - mu1[i] * sc1;
    float sc2 = g2[i] / sqrtf(va2[i] + 1e-5f);
    s2[i] = sc2; t2[i] = b2[i] * sc2 + be2[i] - mu2[i] * sc2;
  }
}

// ---------------------------------------------------------------- 3-NN (v4, MFMA)
__device__ __forceinline__ void top3_insert(float pd, int pi,
    float& d0, float& d1, float& d2v, int& i0, int& i1, int& i2)
{
  bool c0 = (pd < d0) || (pd == d0 && pi < i0);
  bool c1 = (pd < d1) || (pd == d1 && pi < i1);
  bool c2 = (pd < d2v) || (pd == d2v && pi < i2);
  d2v = c1 ? d1 : (c2 ? pd : d2v);
  i2  = c1 ? i1 : (c2 ? pi : i2);
  d1  = c0 ? d0 : (c1 ? pd : d1);
  i1  = c0 ? i0 : (c1 ? pi : i1);
  d0  = c0 ? pd : d0;
  i0  = c0 ? pi : i0;
}

__global__ __launch_bounds__(512)
void knn_kernel(const float* __restrict__ unknown, const f16* __restrict__ bpanel,
                int* __restrict__ idx3, float* __restrict__ w3)
{
  __shared__ f16  Blds[Sdim * 24];     // 49152 B
  __shared__ f16  Alds[8 * 16 * 24];   // 6144 B
  __shared__ float su_lds[8 * 16];
  __shared__ int   cnt[128];
  __shared__ float cd[128][8];
  __shared__ int   ci[128][8];

  int t = threadIdx.x;
  int b = blockIdx.y;
  int lane = t & 63, w = t >> 6;
  int r = lane & 15, g = lane >> 4;

  if (t < 128) cnt[t] = 0;

  {
    const f16* bp = bpanel + (size_t)b * Sdim * 24;
#pragma unroll
    for (int i = 0; i < 6; ++i) {
      int c = t + i * 512;
      async16((char*)Blds + c * 16, (const char*)bp + c * 16);
    }
  }

  int n0 = blockIdx.x * 128 + w * 16;
  if (lane < 16) {
    int n = n0 + lane;
    const float* up = unknown + ((size_t)b * Ndim + n) * 3;
    float x = up[0], y = up[1], z = up[2];
    su_lds[w * 16 + lane] = x * x + y * y + z * z;
    f16 hx = (f16)x, lx = (f16)(x - (float)hx);
    f16 hy = (f16)y, ly = (f16)(y - (float)hy);
    f16 hz = (f16)z, lz = (f16)(z - (float)hz);
    f16* ar = Alds + (w * 16 + lane) * 24;
    f16x8 c0 = {hx, hx, lx, lx, hy, hy, ly, ly};
    f16x8 c1 = {hz, hz, lz, lz, (f16)1.f, (f16)1.f, (f16)0.f, (f16)0.f};
    *(f16x8*)ar = c0;
    *(f16x8*)(ar + 8) = c1;
  }
  __syncthreads();

  f16x8 af = {};
  if (g < 2) af = *(const f16x8*)(Alds + (w * 16 + r) * 24 + g * 8);
  f32x4 su4;
#pragma unroll
  for (int j = 0; j < 4; ++j) su4[j] = su_lds[w * 16 + g * 4 + j];
  int boff = r * 24 + (g & 1) * 8;

  float t0_[4], t1_[4], t2_[4];
#pragma unroll
  for (int j = 0; j < 4; ++j) { t0_[j] = 1e30f; t1_[j] = 1e30f; t2_[j] = 1e30f; }

#pragma unroll 4
  for (int T = 0; T < 64; ++T) {
    f16x8 bf = *(const f16x8*)(Blds + T * 384 + boff);
    f32x4 acc = su4;
    acc = __builtin_amdgcn_mfma_f32_16x16x32_f16(af, bf, acc, 0, 0, 0);
#pragma unroll
    for (int j = 0; j < 4; ++j) {
      float d = acc[j];
      t2_[j] = __builtin_amdgcn_fmed3f(t1_[j], t2_[j], d);
      t1_[j] = __builtin_amdgcn_fmed3f(t0_[j], t1_[j], d);
      t0_[j] = fminf(t0_[j], d);
    }
  }

#pragma unroll
  for (int m = 1; m < 16; m <<= 1) {
#pragma unroll
    for (int j = 0; j < 4; ++j) {
      float b0 = __shfl_xor(t0_[j], m), b1 = __shfl_xor(t1_[j], m), b2 = __shfl_xor(t2_[j], m);
      float n0m = fminf(t0_[j], b0);
      float n1m = fminf(fmaxf(t0_[j], b0), fminf(t1_[j], b1));
      float n2m = fminf(fminf(fmaxf(t0_[j], b1), fmaxf(t1_[j], b0)), fminf(t2_[j], b2));
      t0_[j] = n0m; t1_[j] = n1m; t2_[j] = n2m;
    }
  }

#pragma unroll 2
  for (int T = 0; T < 64; ++T) {
    f16x8 bf = *(const f16x8*)(Blds + T * 384 + boff);
    f32x4 acc = su4;
    acc = __builtin_amdgcn_mfma_f32_16x16x32_f16(af, bf, acc, 0, 0, 0);
    bool h = (acc[0] <= t2_[0]) | (acc[1] <= t2_[1]) |
             (acc[2] <= t2_[2]) | (acc[3] <= t2_[3]);
    if (h) {
#pragma unroll
      for (int j = 0; j < 4; ++j) {
        if (acc[j] <= t2_[j]) {
          int q = w * 16 + g * 4 + j;
          int slot = atomicAdd(&cnt[q], 1);
          if (slot < 8) { cd[q][slot] = acc[j]; ci[q][slot] = T * 16 + r; }
        }
      }
    }
  }
  __syncthreads();

  if (t < 128) {
    int q = t;
    float d0 = 1e30f, d1 = 1e30f, d2v = 1e30f;
    int i0 = 0x7fffffff, i1 = 0x7fffffff, i2 = 0x7fffffff;
    int mc = cnt[q] < 8 ? cnt[q] : 8;
#pragma unroll
    for (int i = 0; i < 8; ++i)
      if (i < mc) top3_insert(cd[q][i], ci[q][i], d0, d1, d2v, i0, i1, i2);
    float wa = 1.0f / (d0 + 1e-8f);
    float wb = 1.0f / (d1 + 1e-8f);
    float wc = 1.0f / (d2v + 1e-8f);
    float wsum = wa + wb + wc;
    int n = blockIdx.x * 128 + q;
    int p = b * Ndim + n;
    idx3[3 * p] = i0; idx3[3 * p + 1] = i1; idx3[3 * p + 2] = i2;
    w3[3 * p] = wa / wsum; w3[3 * p + 1] = wb / wsum; w3[3 * p + 2] = wc / wsum;
  }
}

// ---------------------------------------------------------------- transpose+cast
__global__ void transpose_cast(const float* __restrict__ in, f16* __restrict__ out,
                               int R, int C, int ldo, long inBStride, long outBStride)
{
  __shared__ float tile[32][33];
  const float* src = in + blockIdx.z * inBStride;
  f16* dst = out + blockIdx.z * outBStride;
  int r0 = blockIdx.y * 32, c0 = blockIdx.x * 32;
  int tx = threadIdx.x & 31, ty = threadIdx.x >> 5;
#pragma unroll
  for (int i = 0; i < 4; ++i)
    tile[ty + i * 8][tx] = src[(size_t)(r0 + ty + i * 8) * C + c0 + tx];
  __syncthreads();
#pragma unroll
  for (int i = 0; i < 4; ++i)
    dst[(size_t)(c0 + ty + i * 8) * ldo + r0 + tx] = (f16)tile[tx][ty + i * 8];
}

// ---------------------------------------------------------------- fused GEMM1 (interp folded into B-staging)
// x1[pt*H + o] = relu(scale[o]*sum_k W1[o,k]*feat[pt,k] + shift[o]), where
// feat[pt, 0:256]   = ufT[pt, :]            (staged via global_load_lds, kt 0..3)
// feat[pt, 256:768] = interp(kfT,idx3,w3)   (computed in-regs -> LDS, kt 4..11)
// 128x128 tile, BK=64 (R5 geometry: 128B LDS rows, 8-chunk XOR, 0 conflicts).
__global__ __launch_bounds__(256)
void gemm1_fused(const f16* __restrict__ W1h, const f16* __restrict__ ufT,
                 const f16* __restrict__ kfT, const int* __restrict__ idx3,
                 const float* __restrict__ w3,
                 const float* __restrict__ scale, const float* __restrict__ shift,
                 f16* __restrict__ x1)
{
  __shared__ char lds[65536];  // 2 bufs x (A 16KB + B 16KB)

  int id = blockIdx.x;
  id = (id & 7) * 128 + (id >> 3);        // XCD-chunked swizzle, 1024 blocks
  int big = id >> 1, small = id & 1;
  int m0 = small * 128;                   // output-channel tile
  int n0 = big * 128;                     // point tile
  int b  = n0 >> 12;

  int t = threadIdx.x;
  int lane = t & 63, wid = t >> 6;
  int wm = wid >> 1, wn = wid & 1;
  int lr = lane & 15, lh = lane >> 4;
  int p = t >> 3, x = t & 7;

  // interp metadata: 2 threads per point (pt = t>>1), each covers 4 chunks
  int ptl = t >> 1, qq = t & 1;
  int pg = n0 + ptl;
  int ia = idx3[3 * pg], ib = idx3[3 * pg + 1], ic = idx3[3 * pg + 2];
  float w0 = w3[3 * pg], w1 = w3[3 * pg + 1], w2 = w3[3 * pg + 2];
  const f16* kb = kfT + ((size_t)b << 10) * C2;
  const f16* r0p = kb + (size_t)ia * C2 + qq * 32;
  const f16* r1p = kb + (size_t)ib * C2 + qq * 32;
  const f16* r2p = kb + (size_t)ic * C2 + qq * 32;

  const f16* Arow = W1h + (size_t)m0 * CIN;
  const f16* Brow = ufT + (size_t)n0 * C1;

  auto STAGE_A = [&](int buf, int kt) {
    int k0 = kt * 64;
    char* base = lds + buf * 32768;
#pragma unroll
    for (int r = 0; r < 4; ++r) {
      int row = r * 32 + p;
      int sw = (x ^ (row & 7)) * 8;
      async16(base + r * 4096 + t * 16, Arow + (size_t)row * CIN + k0 + sw);
    }
  };
  auto STAGE_B_uf = [&](int buf, int kt) {
    int k0 = kt * 64;
    char* base = lds + buf * 32768 + 16384;
#pragma unroll
    for (int r = 0; r < 4; ++r) {
      int row = r * 32 + p;
      int sw = (x ^ (row & 7)) * 8;
      async16(base + r * 4096 + t * 16, Brow + (size_t)row * C1 + k0 + sw);
    }
  };
  auto STAGE_B_interp = [&](int buf, int kt) {
    char* base = lds + buf * 32768 + 16384;
    int e0 = (kt - 4) * 64;   // element offset within kfT row
#pragma unroll
    for (int i = 0; i < 4; ++i) {
      int g = qq * 4 + i;
      f16x8 a = *(const f16x8*)(r0p + e0 + i * 8);
      f16x8 c = *(const f16x8*)(r1p + e0 + i * 8);
      f16x8 d = *(const f16x8*)(r2p + e0 + i * 8);
      f16x8 o;
#pragma unroll
      for (int j = 0; j < 8; ++j)
        o[j] = (f16)(w0 * (float)a[j] + w1 * (float)c[j] + w2 * (float)d[j]);
      *(f16x8*)(base + ptl * 128 + ((g ^ (ptl & 7)) << 4)) = o;
    }
  };

  f32x4 acc[4][4] = {};

  STAGE_A(0, 0);
  STAGE_B_uf(0, 0);
  __syncthreads();
#pragma unroll
  for (int kt = 0; kt < 12; ++kt) {
    int cb = kt & 1, nb = cb ^ 1;
    if (kt + 1 < 12) {
      STAGE_A(nb, kt + 1);
      if (kt + 1 < 4) STAGE_B_uf(nb, kt + 1);
      else            STAGE_B_interp(nb, kt + 1);
    }
    const char* Ab = lds + cb * 32768;
    const char* Bb = Ab + 16384;
#pragma unroll
    for (int kk = 0; kk < 2; ++kk) {
      f16x8 af[4], bf[4];
#pragma unroll
      for (int mf = 0; mf < 4; ++mf) {
        int row = wm * 64 + mf * 16 + lr;
        int g = kk * 4 + lh;
        af[mf] = *(const f16x8*)(Ab + row * 128 + ((g ^ (row & 7)) << 4));
      }
#pragma unroll
      for (int nf = 0; nf < 4; ++nf) {
        int row = wn * 64 + nf * 16 + lr;
        int g = kk * 4 + lh;
        bf[nf] = *(const f16x8*)(Bb + row * 128 + ((g ^ (row & 7)) << 4));
      }
#pragma unroll
      for (int mf = 0; mf < 4; ++mf)
#pragma unroll
        for (int nf = 0; nf < 4; ++nf)
          acc[mf][nf] = __builtin_amdgcn_mfma_f32_16x16x32_f16(af[mf], bf[nf], acc[mf][nf], 0, 0, 0);
    }
    __syncthreads();
  }

  // epilogue: BN+ReLU, write x1 point-major fp16
#pragma unroll
  for (int mf = 0; mf < 4; ++mf) {
    int ob = m0 + wm * 64 + mf * 16 + lh * 4;
    f32x4 sc = *(const f32x4*)(scale + ob);
    f32x4 sh = *(const f32x4*)(shift + ob);
#pragma unroll
    for (int nf = 0; nf < 4; ++nf) {
      int ptc = n0 + wn * 64 + nf * 16 + lr;
      f16x4 v;
#pragma unroll
      for (int j = 0; j < 4; ++j) {
        float y = acc[mf][nf][j] * sc[j] + sh[j];
        v[j] = (f16)(y > 0.0f ? y : 0.0f);
      }
      *(f16x4*)(x1 + (size_t)ptc * H + ob) = v;
    }
  }
}

// ---------------------------------------------------------------- GEMM2 (R5 structure, BK=64)
// out fp32 d_out[(b*H+o)*N + n]; A = x1 (pt-major, K=256), Bt = W2h (o-major).
template <int K>
__global__ __launch_bounds__(256)
void gemm2_kernel(const f16* __restrict__ A, const f16* __restrict__ Bt,
                  const float* __restrict__ scale, const float* __restrict__ shift,
                  float* __restrict__ out)
{
  __shared__ char lds[65536];

  int id = blockIdx.x;
  id = (id & 7) * 128 + (id >> 3);
  int big = id >> 1, small = id & 1;
  int m0 = big * 128;                     // point tile
  int n0 = small * 128;                   // output-channel tile

  int t = threadIdx.x;
  int lane = t & 63, wid = t >> 6;
  int wm = wid >> 1, wn = wid & 1;
  int lr = lane & 15, lh = lane >> 4;

  f32x4 acc[4][4] = {};

  constexpr int NT = K / 64;
  const f16* Arow = A + (size_t)m0 * K;
  const f16* Brow = Bt + (size_t)n0 * K;
  int p = t >> 3, x = t & 7;

  auto STAGE = [&](int buf, int kt) {
    int k0 = kt * 64;
    char* base = lds + buf * 32768;
#pragma unroll
    for (int r = 0; r < 4; ++r) {
      int row = r * 32 + p;
      int sw = (x ^ (row & 7)) * 8;
      async16(base + r * 4096 + t * 16,         Arow + (size_t)row * K + k0 + sw);
      async16(base + 16384 + r * 4096 + t * 16, Brow + (size_t)row * K + k0 + sw);
    }
  };

  STAGE(0, 0);
  __syncthreads();
  int cur = 0;
  for (int kt = 0; kt < NT; ++kt) {
    if (kt + 1 < NT) STAGE(cur ^ 1, kt + 1);
    const char* Ab = lds + cur * 32768;
    const char* Bb = Ab + 16384;
#pragma unroll
    for (int kk = 0; kk < 2; ++kk) {
      f16x8 af[4], bf[4];
#pragma unroll
      for (int mf = 0; mf < 4; ++mf) {
        int row = wm * 64 + mf * 16 + lr;
        int g = kk * 4 + lh;
        af[mf] = *(const f16x8*)(Ab + row * 128 + ((g ^ (row & 7)) << 4));
      }
#pragma unroll
      for (int nf = 0; nf < 4; ++nf) {
        int row = wn * 64 + nf * 16 + lr;
        int g = kk * 4 + lh;
        bf[nf] = *(const f16x8*)(Bb + row * 128 + ((g ^ (row & 7)) << 4));
      }
#pragma unroll
      for (int mf = 0; mf < 4; ++mf)
#pragma unroll
        for (int nf = 0; nf < 4; ++nf)
          acc[mf][nf] = __builtin_amdgcn_mfma_f32_16x16x32_f16(af[mf], bf[nf], acc[mf][nf], 0, 0, 0);
    }
    __syncthreads();
    cur ^= 1;
  }

#pragma unroll
  for (int mf = 0; mf < 4; ++mf) {
    int ptb = m0 + wm * 64 + mf * 16 + lh * 4;
    int bb = ptb >> 12, nn = ptb & 4095;
#pragma unroll
    for (int nf = 0; nf < 4; ++nf) {
      int o = n0 + wn * 64 + nf * 16 + lr;
      float sc = scale[o], sh = shift[o];
      f32x4 v;
#pragma unroll
      for (int j = 0; j < 4; ++j) {
        float y = acc[mf][nf][j] * sc + sh;
        v[j] = (y > 0.0f ? y : 0.0f);
      }
      *(f32x4*)(out + ((size_t)(bb * H + o) << 12) + nn) = v;
    }
  }
}

// ---------------------------------------------------------------- launch
extern "C" void kernel_launch(void* const* d_in, const int* in_sizes, int n_in,
                              void* d_out, int out_size, void* d_ws, size_t ws_size,
                              hipStream_t stream)
{
  (void)in_sizes; (void)n_in; (void)out_size; (void)ws_size;
  const float* unknown = (const float*)d_in[0];
  const float* known   = (const float*)d_in[1];
  const float* uf      = (const float*)d_in[2];
  const float* kf      = (const float*)d_in[3];
  const float* W1  = (const float*)d_in[4];
  const float* b1  = (const float*)d_in[5];
  const float* g1  = (const float*)d_in[6];
  const float* be1 = (const float*)d_in[7];
  const float* mu1 = (const float*)d_in[8];
  const float* va1 = (const float*)d_in[9];
  const float* W2  = (const float*)d_in[10];
  const float* b2  = (const float*)d_in[11];
  const float* g2  = (const float*)d_in[12];
  const float* be2 = (const float*)d_in[13];
  const float* mu2 = (const float*)d_in[14];
  const float* va2 = (const float*)d_in[15];

  char* ws = (char*)d_ws;
  f16*   W1h    = (f16*)(ws + 0);             //    393,216 B
  f16*   W2h    = (f16*)(ws + 393216);        //    131,072 B
  float* s1     = (float*)(ws + 524288);
  float* t1     = (float*)(ws + 525312);
  float* s2     = (float*)(ws + 526336);
  float* t2     = (float*)(ws + 527360);
  int*   idx3   = (int*)(ws + 528384);        //    786,432 B
  float* w3     = (float*)(ws + 1314816);     //    786,432 B
  f16*   bpanel = (f16*)(ws + 2101248);       //    786,432 B
  f16*   kfT    = (f16*)(ws + 2887680);       // 16,777,216 B  (B,S,C2) fp16
  f16*   ufT    = (f16*)(ws + 19664896);      // 33,554,432 B  (pts, C1) fp16
  f16*   x1     = (f16*)(ws + 53219328);      // 33,554,432 B  (pts, H) fp16
                                              // total 86,773,760 B

  prep_kernel<<<768, 256, 0, stream>>>(W1, W2, b1, g1, be1, mu1, va1,
                                       b2, g2, be2, mu2, va2, known,
                                       W1h, W2h, bpanel, s1, t1, s2, t2);
  knn_kernel<<<dim3(Ndim / 128, Bdim), 512, 0, stream>>>(unknown, bpanel, idx3, w3);
  transpose_cast<<<dim3(Sdim / 32, C2 / 32, Bdim), 256, 0, stream>>>(
      kf, kfT, C2, Sdim, C2, (long)C2 * Sdim, (long)Sdim * C2);
  transpose_cast<<<dim3(Ndim / 32, C1 / 32, Bdim), 256, 0, stream>>>(
      uf, ufT, C1, Ndim, C1, (long)C1 * Ndim, (long)Ndim * C1);
  gemm1_fused<<<1024, 256, 0, stream>>>(W1h, ufT, kfT, idx3, w3, s1, t1, x1);
  gemm2_kernel<H><<<1024, 256, 0, stream>>>(x1, W2h, s2, t2, (float*)d_out);
}